// Round 10
// baseline (163.389 us; speedup 1.0000x reference)
//
#include <hip/hip_runtime.h>

#define NN 256
#define DIN 32
#define DD 64
#define D2 128
#define RTOT 4096      // BB*NN rows
#define GBC 512        // bc blocks (2 per CU)
#define RPC 8          // rows per bc block
#define GBD 1024       // d blocks (4 rows each)

typedef float f32x4 __attribute__((ext_vector_type(4)));
typedef float f32x2 __attribute__((ext_vector_type(2)));

__device__ __forceinline__ void fma4(f32x4& o, float s, const f32x4 w) {
  o[0] = fmaf(s, w[0], o[0]); o[1] = fmaf(s, w[1], o[1]);
  o[2] = fmaf(s, w[2], o[2]); o[3] = fmaf(s, w[3], o[3]);
}

// x[r,c] = fea[r,:] @ encW + encb ; block 0 also zeroes the stat accumulators
__global__ __launch_bounds__(256) void enc_kernel(
    const float* __restrict__ fea, const float* __restrict__ W,
    const float* __restrict__ bias, float* __restrict__ x,
    float* __restrict__ accz) {
  if (blockIdx.x == 0) {
#pragma unroll
    for (int i = 0; i < 6; ++i) accz[threadIdx.x + i * 256] = 0.f;
  }
  int g = blockIdx.x * 256 + threadIdx.x;
  int r = g >> 6, c = g & 63;
  const float* fr = fea + r * DIN;
  float acc = bias[c];
#pragma unroll
  for (int k = 0; k < DIN; ++k) acc = fmaf(fr[k], W[k * DD + c], acc);
  x[g] = acc;
}

// bc: whole-batch Y staged once in LDS; ballot agg; MLP1 with global weights.
// acc layout per layer (stride 512): s1[128]@0 q1[128]@128 s2[64]@256 q2[64]@320
__global__ __launch_bounds__(256) void bc_kernel(
    const float* __restrict__ adj, const float* __restrict__ x,
    const float* __restrict__ bondW, const float* __restrict__ epsp,
    const float* __restrict__ W1, const float* __restrict__ b1,
    const float* __restrict__ gbnp, const float* __restrict__ bbnp,
    const float* __restrict__ acc2p,   // prev layer: s2@0, q2@64
    int apply_bn,
    float* __restrict__ h1, float* __restrict__ acc1) {
  __shared__ float sY[NN * DD];        // 64 KB: transformed y for the whole batch
  __shared__ float sh[RPC * DD];       // 2 KB
  __shared__ float sSB[2 * DD];        // prev BN2 affine
  __shared__ float pst[2 * RPC * D2];  // 8 KB: MLP1 stat partials
  const int tid = threadIdx.x, bid = blockIdx.x;
  const int lane = tid & 63, wv = tid >> 6;
  const int b = bid >> 5;              // 32 blocks per batch
  const int r0 = (bid & 31) * RPC;     // row offset within batch

  if (apply_bn && tid < DD) {
    float s = acc2p[tid], q = acc2p[64 + tid];
    float mean = s * (1.f / RTOT);
    float var = fmaf(-mean, mean, q * (1.f / RTOT));
    float sc = gbnp[tid] * rsqrtf(var + 1e-5f);
    sSB[tid] = sc;
    sSB[64 + tid] = fmaf(-mean, sc, bbnp[tid]);
  }
  __syncthreads();

  const float* xb = x + (size_t)b * NN * DD;

  // ---- issue ALL global reads in one burst: adj rows, own-row x, batch Y ----
  float a[2][4];                       // this wave's 2 rows x 4 adj chunks
#pragma unroll
  for (int rr = 0; rr < 2; ++rr) {
    const float* adjr = adj + ((size_t)b * NN + r0 + wv * 2 + rr) * NN + lane;
#pragma unroll
    for (int ck = 0; ck < 4; ++ck) a[rr][ck] = adjr[ck * 64];
  }
  float xo[2];
#pragma unroll
  for (int rr = 0; rr < 2; ++rr)
    xo[rr] = xb[(size_t)(r0 + wv * 2 + rr) * DD + lane];
  f32x4 yv[16];
  {
    const f32x4* xb4 = (const f32x4*)xb;
#pragma unroll
    for (int k = 0; k < 16; ++k) yv[k] = xb4[tid + k * 256];
  }

  unsigned long long m[2][4];
#pragma unroll
  for (int rr = 0; rr < 2; ++rr)
#pragma unroll
    for (int ck = 0; ck < 4; ++ck) m[rr][ck] = __ballot(a[rr][ck] != 0.f);

  // ---- transform + store Y to LDS (one vmcnt drain total) ----
  {
    const int d0 = (tid & 15) * 4;     // this thread's column group (constant)
    f32x4 bw4 = *(const f32x4*)&bondW[d0];
    f32x4 aS = {0, 0, 0, 0}, aB = {0, 0, 0, 0};
    if (apply_bn) { aS = *(const f32x4*)&sSB[d0]; aB = *(const f32x4*)&sSB[64 + d0]; }
    f32x4* sy4 = (f32x4*)sY;
#pragma unroll
    for (int k = 0; k < 16; ++k) {
      f32x4 v = yv[k];
#pragma unroll
      for (int e = 0; e < 4; ++e) {
        float t = v[e];
        if (apply_bn) t = fmaxf(fmaf(t, aS[e], aB[e]), 0.f);
        v[e] = fmaxf(t + bw4[e], 0.f);
      }
      sy4[tid + k * 256] = v;
    }
  }
  __syncthreads();

  // ---- agg: per row, per chunk, 8-batched LDS gathers; no more syncs ----
  float S = 0.f, Bv = 0.f;
  if (apply_bn) { S = sSB[lane]; Bv = sSB[64 + lane]; }
  float epv = 1.f + epsp[0];
#pragma unroll
  for (int rr = 0; rr < 2; ++rr) {
    float av = 0.f;
#pragma unroll
    for (int ck = 0; ck < 4; ++ck) {
      unsigned long long mm = m[rr][ck];
      const float* yb = sY + ck * 64 * DD + lane;
      while (mm) {
        float v[8]; bool hb[8];
#pragma unroll
        for (int u = 0; u < 8; ++u) {
          bool ok = mm != 0ull;
          int j = ok ? (int)__builtin_ctzll(mm) : 0;
          mm &= mm - 1;
          hb[u] = ok;
          v[u] = yb[j * DD];
        }
#pragma unroll
        for (int u = 0; u < 8; ++u) av += hb[u] ? v[u] : 0.f;
      }
    }
    float xv = xo[rr];
    if (apply_bn) xv = fmaxf(fmaf(xv, S, Bv), 0.f);
    sh[(wv * 2 + rr) * DD + lane] = fmaf(epv, xv, av);
  }
  __syncthreads();

  // ---- MLP1: 8x128 tile, thread = 1 row x 4 cols, weights from global ----
  {
    int row = tid >> 5, c0 = (tid & 31) * 4;
    f32x4 o = *(const f32x4*)&b1[c0];
#pragma unroll 4
    for (int d = 0; d < DD; d += 4) {
      f32x4 hv = *(const f32x4*)&sh[row * DD + d];
      f32x4 w0 = *(const f32x4*)&W1[(d + 0) * D2 + c0];
      f32x4 w1 = *(const f32x4*)&W1[(d + 1) * D2 + c0];
      f32x4 w2 = *(const f32x4*)&W1[(d + 2) * D2 + c0];
      f32x4 w3 = *(const f32x4*)&W1[(d + 3) * D2 + c0];
      fma4(o, hv[0], w0); fma4(o, hv[1], w1); fma4(o, hv[2], w2); fma4(o, hv[3], w3);
    }
    *(f32x4*)&h1[(size_t)(b * NN + r0 + row) * D2 + c0] = o;
    *(f32x4*)&pst[row * D2 + c0] = o;
    *(f32x4*)&pst[RPC * D2 + row * D2 + c0] = o * o;
  }
  __syncthreads();
  if (tid < D2) {
    float s = 0.f, q = 0.f;
#pragma unroll
    for (int g = 0; g < RPC; ++g) {
      s += pst[g * D2 + tid];
      q += pst[RPC * D2 + g * D2 + tid];
    }
    atomicAdd(acc1 + tid, s);
    atomicAdd(acc1 + 128 + tid, q);
  }
}

// d: BN1 (from acc) + ReLU + MLP2 -> raw h2 (into x) + atomic BN2 stats.
// 1024 blocks x 4 rows: small LDS (~5 KB) -> 4+ blocks/CU, 16 waves/CU.
// Weights read straight from global (L2-hot, lane-coalesced).
__global__ __launch_bounds__(256) void d_kernel(
    const float* __restrict__ h1, const float* __restrict__ W2,
    const float* __restrict__ b2, const float* __restrict__ g1,
    const float* __restrict__ be1, float* __restrict__ h2,
    const float* __restrict__ acc1,    // s1@0 q1@128
    float* __restrict__ acc2) {        // s2@0 q2@64
  __shared__ float sS[D2], sB[D2];
  __shared__ float sh1[4][D2];
  __shared__ float pst[2][4][DD];
  const int tid = threadIdx.x, bid = blockIdx.x;
  const int row = tid >> 6, lane = tid & 63;

  if (tid < D2) {
    float mean = acc1[tid] * (1.f / RTOT);
    float var = fmaf(-mean, mean, acc1[128 + tid] * (1.f / RTOT));
    float sc = g1[tid] * rsqrtf(var + 1e-5f);
    sS[tid] = sc;
    sB[tid] = fmaf(-mean, sc, be1[tid]);
  }
  __syncthreads();
  {
    int gr = bid * 4 + row;
    int c = lane * 2;
    f32x2 v = *(const f32x2*)(h1 + (size_t)gr * D2 + c);
    v[0] = fmaxf(fmaf(v[0], sS[c + 0], sB[c + 0]), 0.f);
    v[1] = fmaxf(fmaf(v[1], sS[c + 1], sB[c + 1]), 0.f);
    *(f32x2*)&sh1[row][c] = v;
  }
  __syncthreads();
  {
    // thread = (row, out-col lane): 128 pipelined global weight loads,
    // sh1[row][c] is a wave-broadcast (whole wave = one row)
    float o = b2[lane];
#pragma unroll 8
    for (int c = 0; c < D2; ++c)
      o = fmaf(sh1[row][c], W2[c * DD + lane], o);
    int gr = bid * 4 + row;
    h2[(size_t)gr * DD + lane] = o;
    pst[0][row][lane] = o;
    pst[1][row][lane] = o * o;
  }
  __syncthreads();
  if (tid < DD) {
    float s = pst[0][0][tid] + pst[0][1][tid] + pst[0][2][tid] + pst[0][3][tid];
    float q = pst[1][0][tid] + pst[1][1][tid] + pst[1][2][tid] + pst[1][3][tid];
    atomicAdd(acc2 + tid, s);
    atomicAdd(acc2 + 64 + tid, q);
  }
}

// fin: BN2 (no relu) from acc -> out
__global__ __launch_bounds__(256) void fin_kernel(
    const float* __restrict__ h2, const float* __restrict__ gbn,
    const float* __restrict__ bbn, const float* __restrict__ acc2,
    float* __restrict__ outp) {
  __shared__ float sS2[DD], sB2[DD];
  int tid = threadIdx.x, bid = blockIdx.x;
  if (tid < 64) {
    float mean = acc2[tid] * (1.f / RTOT);
    float var = fmaf(-mean, mean, acc2[64 + tid] * (1.f / RTOT));
    float sc = gbn[tid] * rsqrtf(var + 1e-5f);
    sS2[tid] = sc;
    sB2[tid] = fmaf(-mean, sc, bbn[tid]);
  }
  __syncthreads();
#pragma unroll
  for (int k = 0; k < 4; ++k) {
    int idx = bid * 1024 + k * 256 + tid;
    int c = idx & 63;
    outp[idx] = fmaf(h2[idx], sS2[c], sB2[c]);
  }
}

extern "C" void kernel_launch(void* const* d_in, const int* in_sizes, int n_in,
                              void* d_out, int out_size, void* d_ws, size_t ws_size,
                              hipStream_t stream) {
  const float* fea  = (const float*)d_in[0];
  const float* adj  = (const float*)d_in[1];
  const float* encW = (const float*)d_in[2];
  const float* encb = (const float*)d_in[3];
  const float* bondW= (const float*)d_in[4];
  const float* eps  = (const float*)d_in[5];
  const float* W1   = (const float*)d_in[6];
  const float* b1   = (const float*)d_in[7];
  const float* g1   = (const float*)d_in[8];
  const float* be1  = (const float*)d_in[9];
  const float* W2   = (const float*)d_in[10];
  const float* b2   = (const float*)d_in[11];
  const float* gbn  = (const float*)d_in[12];
  const float* bbn  = (const float*)d_in[13];
  float* out = (float*)d_out;
  float* ws  = (float*)d_ws;

  float* x   = ws;                 // 262144 floats (enc out / raw h2)
  float* h1  = ws + 262144;        // 524288 floats
  float* acc = ws + 786432;        // 3 layers x 512 floats of stat accumulators

  enc_kernel<<<1024, 256, 0, stream>>>(fea, encW, encb, x, acc);
  for (int l = 0; l < 3; ++l) {
    bc_kernel<<<GBC, 256, 0, stream>>>(
        adj, x, bondW + l * DD, eps + l, W1 + l * DD * D2, b1 + l * D2,
        l ? gbn + (l - 1) * DD : gbn, l ? bbn + (l - 1) * DD : bbn,
        l ? acc + (l - 1) * 512 + 256 : acc, l > 0 ? 1 : 0,
        h1, acc + l * 512);
    d_kernel<<<GBD, 256, 0, stream>>>(h1, W2 + l * D2 * DD, b2 + l * DD,
                                      g1 + l * D2, be1 + l * D2, x,
                                      acc + l * 512, acc + l * 512 + 256);
  }
  fin_kernel<<<256, 256, 0, stream>>>(x, gbn + 2 * DD, bbn + 2 * DD,
                                      acc + 2 * 512 + 256, out);
}

// Round 11
// 87.162 us; speedup vs baseline: 1.8746x; 1.8746x over previous
//
#include <hip/hip_runtime.h>

#define NN 256
#define DIN 32
#define DD 64
#define D2 128
#define RTOT 4096      // BB*NN rows
#define GBD 256        // d/fin blocks
#define RPB 16         // rows per d/fin block
#define GBC 512        // bc blocks (2 per CU)
#define RPC 8          // rows per bc block
#define AST 32         // acc stat stride in floats (128 B = 1 L2 line per channel)

typedef float f32x4 __attribute__((ext_vector_type(4)));
typedef float f32x2 __attribute__((ext_vector_type(2)));

__device__ __forceinline__ void fma4(f32x4& o, float s, const f32x4 w) {
  o[0] = fmaf(s, w[0], o[0]); o[1] = fmaf(s, w[1], o[1]);
  o[2] = fmaf(s, w[2], o[2]); o[3] = fmaf(s, w[3], o[3]);
}

// x[r,c] = fea[r,:] @ encW + encb ; first 48 blocks also zero the padded accs
__global__ __launch_bounds__(256) void enc_kernel(
    const float* __restrict__ fea, const float* __restrict__ W,
    const float* __restrict__ bias, float* __restrict__ x,
    float* __restrict__ accz) {
  if (blockIdx.x < 48) {     // 48 * 1024 = 49152 = 3 * 512 * AST
#pragma unroll
    for (int i = 0; i < 4; ++i)
      accz[blockIdx.x * 1024 + i * 256 + threadIdx.x] = 0.f;
  }
  int g = blockIdx.x * 256 + threadIdx.x;
  int r = g >> 6, c = g & 63;
  const float* fr = fea + r * DIN;
  float acc = bias[c];
#pragma unroll
  for (int k = 0; k < DIN; ++k) acc = fmaf(fr[k], W[k * DD + c], acc);
  x[g] = acc;
}

// bc: whole-batch Y staged once in LDS; ballot agg; MLP1 with global weights.
// acc slots (per layer, each slot padded by AST): s1[c]@c, q1[c]@128+c,
// s2[c]@256+c, q2[c]@320+c
__global__ __launch_bounds__(256) void bc_kernel(
    const float* __restrict__ adj, const float* __restrict__ x,
    const float* __restrict__ bondW, const float* __restrict__ epsp,
    const float* __restrict__ W1, const float* __restrict__ b1,
    const float* __restrict__ gbnp, const float* __restrict__ bbnp,
    const float* __restrict__ acc2p,   // prev layer s2 base (padded)
    int apply_bn,
    float* __restrict__ h1, float* __restrict__ acc1) {
  __shared__ float sY[NN * DD];        // 64 KB
  __shared__ float sh[RPC * DD];       // 2 KB
  __shared__ float sSB[2 * DD];
  __shared__ float pst[2 * RPC * D2];  // 8 KB
  const int tid = threadIdx.x, bid = blockIdx.x;
  const int lane = tid & 63, wv = tid >> 6;
  const int b = bid >> 5;              // 32 blocks per batch
  const int r0 = (bid & 31) * RPC;

  if (apply_bn && tid < DD) {
    float s = acc2p[tid * AST], q = acc2p[(64 + tid) * AST];
    float mean = s * (1.f / RTOT);
    float var = fmaf(-mean, mean, q * (1.f / RTOT));
    float sc = gbnp[tid] * rsqrtf(var + 1e-5f);
    sSB[tid] = sc;
    sSB[64 + tid] = fmaf(-mean, sc, bbnp[tid]);
  }
  __syncthreads();

  const float* xb = x + (size_t)b * NN * DD;

  // ---- issue ALL global reads in one burst ----
  float a[2][4];
#pragma unroll
  for (int rr = 0; rr < 2; ++rr) {
    const float* adjr = adj + ((size_t)b * NN + r0 + wv * 2 + rr) * NN + lane;
#pragma unroll
    for (int ck = 0; ck < 4; ++ck) a[rr][ck] = adjr[ck * 64];
  }
  float xo[2];
#pragma unroll
  for (int rr = 0; rr < 2; ++rr)
    xo[rr] = xb[(size_t)(r0 + wv * 2 + rr) * DD + lane];
  f32x4 yv[16];
  {
    const f32x4* xb4 = (const f32x4*)xb;
#pragma unroll
    for (int k = 0; k < 16; ++k) yv[k] = xb4[tid + k * 256];
  }

  unsigned long long m[2][4];
#pragma unroll
  for (int rr = 0; rr < 2; ++rr)
#pragma unroll
    for (int ck = 0; ck < 4; ++ck) m[rr][ck] = __ballot(a[rr][ck] != 0.f);

  // ---- transform + store Y to LDS (one vmcnt drain) ----
  {
    const int d0 = (tid & 15) * 4;
    f32x4 bw4 = *(const f32x4*)&bondW[d0];
    f32x4 aS = {0, 0, 0, 0}, aB = {0, 0, 0, 0};
    if (apply_bn) { aS = *(const f32x4*)&sSB[d0]; aB = *(const f32x4*)&sSB[64 + d0]; }
    f32x4* sy4 = (f32x4*)sY;
#pragma unroll
    for (int k = 0; k < 16; ++k) {
      f32x4 v = yv[k];
#pragma unroll
      for (int e = 0; e < 4; ++e) {
        float t = v[e];
        if (apply_bn) t = fmaxf(fmaf(t, aS[e], aB[e]), 0.f);
        v[e] = fmaxf(t + bw4[e], 0.f);
      }
      sy4[tid + k * 256] = v;
    }
  }
  __syncthreads();

  // ---- agg: 8-batched LDS gathers ----
  float S = 0.f, Bv = 0.f;
  if (apply_bn) { S = sSB[lane]; Bv = sSB[64 + lane]; }
  float epv = 1.f + epsp[0];
#pragma unroll
  for (int rr = 0; rr < 2; ++rr) {
    float av = 0.f;
#pragma unroll
    for (int ck = 0; ck < 4; ++ck) {
      unsigned long long mm = m[rr][ck];
      const float* yb = sY + ck * 64 * DD + lane;
      while (mm) {
        float v[8]; bool hb[8];
#pragma unroll
        for (int u = 0; u < 8; ++u) {
          bool ok = mm != 0ull;
          int j = ok ? (int)__builtin_ctzll(mm) : 0;
          mm &= mm - 1;
          hb[u] = ok;
          v[u] = yb[j * DD];
        }
#pragma unroll
        for (int u = 0; u < 8; ++u) av += hb[u] ? v[u] : 0.f;
      }
    }
    float xv = xo[rr];
    if (apply_bn) xv = fmaxf(fmaf(xv, S, Bv), 0.f);
    sh[(wv * 2 + rr) * DD + lane] = fmaf(epv, xv, av);
  }
  __syncthreads();

  // ---- MLP1: 8x128 tile, thread = 1 row x 4 cols, weights from global ----
  {
    int row = tid >> 5, c0 = (tid & 31) * 4;
    f32x4 o = *(const f32x4*)&b1[c0];
#pragma unroll 4
    for (int d = 0; d < DD; d += 4) {
      f32x4 hv = *(const f32x4*)&sh[row * DD + d];
      f32x4 w0 = *(const f32x4*)&W1[(d + 0) * D2 + c0];
      f32x4 w1 = *(const f32x4*)&W1[(d + 1) * D2 + c0];
      f32x4 w2 = *(const f32x4*)&W1[(d + 2) * D2 + c0];
      f32x4 w3 = *(const f32x4*)&W1[(d + 3) * D2 + c0];
      fma4(o, hv[0], w0); fma4(o, hv[1], w1); fma4(o, hv[2], w2); fma4(o, hv[3], w3);
    }
    *(f32x4*)&h1[(size_t)(b * NN + r0 + row) * D2 + c0] = o;
    *(f32x4*)&pst[row * D2 + c0] = o;
    *(f32x4*)&pst[RPC * D2 + row * D2 + c0] = o * o;
  }
  __syncthreads();
  if (tid < D2) {
    float s = 0.f, q = 0.f;
#pragma unroll
    for (int g = 0; g < RPC; ++g) {
      s += pst[g * D2 + tid];
      q += pst[RPC * D2 + g * D2 + tid];
    }
    atomicAdd(acc1 + tid * AST, s);            // 1 line per channel
    atomicAdd(acc1 + (128 + tid) * AST, q);
  }
}

// d: BN1 (from padded acc) + ReLU + MLP2 -> raw h2 (into x) + padded BN2 stats
__global__ __launch_bounds__(256) void d_kernel(
    const float* __restrict__ h1, const float* __restrict__ W2,
    const float* __restrict__ b2, const float* __restrict__ g1,
    const float* __restrict__ be1, float* __restrict__ h2,
    const float* __restrict__ acc1,
    float* __restrict__ acc2) {
  __shared__ float sW2[D2 * DD];          // 32 KB
  __shared__ float sh1[RPB][D2 + 4];
  __shared__ float sS[D2], sB[D2];
  __shared__ float pst[2 * 8 * DD];       // 4 KB
  int tid = threadIdx.x, bid = blockIdx.x;

  {
    const f32x4* w4 = (const f32x4*)W2;
    f32x4* s4 = (f32x4*)sW2;
#pragma unroll
    for (int i = 0; i < 8; ++i) s4[tid + i * 256] = w4[tid + i * 256];
  }
  if (tid < D2) {
    float mean = acc1[tid * AST] * (1.f / RTOT);
    float var = fmaf(-mean, mean, acc1[(128 + tid) * AST] * (1.f / RTOT));
    float sc = g1[tid] * rsqrtf(var + 1e-5f);
    sS[tid] = sc;
    sB[tid] = fmaf(-mean, sc, be1[tid]);
  }
  __syncthreads();
  {
    const f32x4* h14 = (const f32x4*)(h1 + (size_t)bid * RPB * D2);
#pragma unroll
    for (int ii = 0; ii < 2; ++ii) {
      int i = tid + ii * 256;
      f32x4 v = h14[i];
      int lr = i >> 5, c = (i & 31) * 4;
      v[0] = fmaxf(fmaf(v[0], sS[c + 0], sB[c + 0]), 0.f);
      v[1] = fmaxf(fmaf(v[1], sS[c + 1], sB[c + 1]), 0.f);
      v[2] = fmaxf(fmaf(v[2], sS[c + 2], sB[c + 2]), 0.f);
      v[3] = fmaxf(fmaf(v[3], sS[c + 3], sB[c + 3]), 0.f);
      *(f32x4*)&sh1[lr][c] = v;
    }
  }
  __syncthreads();

  // MLP2: 16x64 tile; 128 threads, each 2 rows x 4 cols
  float* pssum = pst;
  float* pssq  = pst + 8 * DD;
  if (tid < 128) {
    int rg = tid >> 4;
    int c0 = (tid & 15) * 4;
    f32x4 bv = *(const f32x4*)&b2[c0];
    f32x4 o0 = bv, o1 = bv;
    for (int c = 0; c < D2; c += 4) {
      f32x4 s0 = *(const f32x4*)&sh1[rg * 2 + 0][c];
      f32x4 s1 = *(const f32x4*)&sh1[rg * 2 + 1][c];
      f32x4 w0 = *(const f32x4*)&sW2[(c + 0) * DD + c0];
      f32x4 w1 = *(const f32x4*)&sW2[(c + 1) * DD + c0];
      f32x4 w2 = *(const f32x4*)&sW2[(c + 2) * DD + c0];
      f32x4 w3 = *(const f32x4*)&sW2[(c + 3) * DD + c0];
      fma4(o0, s0[0], w0); fma4(o0, s0[1], w1); fma4(o0, s0[2], w2); fma4(o0, s0[3], w3);
      fma4(o1, s1[0], w0); fma4(o1, s1[1], w1); fma4(o1, s1[2], w2); fma4(o1, s1[3], w3);
    }
    size_t gr = (size_t)(bid * RPB + rg * 2) * DD + c0;
    *(f32x4*)&h2[gr] = o0;
    *(f32x4*)&h2[gr + DD] = o1;
    *(f32x4*)&pssum[rg * DD + c0] = o0 + o1;
    *(f32x4*)&pssq[rg * DD + c0] = o0 * o0 + o1 * o1;
  }
  __syncthreads();
  if (tid < DD) {
    float s = 0.f, q = 0.f;
#pragma unroll
    for (int g = 0; g < 8; ++g) { s += pssum[g * DD + tid]; q += pssq[g * DD + tid]; }
    atomicAdd(acc2 + tid * AST, s);
    atomicAdd(acc2 + (64 + tid) * AST, q);
  }
}

// fin: BN2 (no relu) from padded acc -> out
__global__ __launch_bounds__(256) void fin_kernel(
    const float* __restrict__ h2, const float* __restrict__ gbn,
    const float* __restrict__ bbn, const float* __restrict__ acc2,
    float* __restrict__ outp) {
  __shared__ float sS2[DD], sB2[DD];
  int tid = threadIdx.x, bid = blockIdx.x;
  if (tid < 64) {
    float mean = acc2[tid * AST] * (1.f / RTOT);
    float var = fmaf(-mean, mean, acc2[(64 + tid) * AST] * (1.f / RTOT));
    float sc = gbn[tid] * rsqrtf(var + 1e-5f);
    sS2[tid] = sc;
    sB2[tid] = fmaf(-mean, sc, bbn[tid]);
  }
  __syncthreads();
#pragma unroll
  for (int k = 0; k < 4; ++k) {
    int idx = bid * 1024 + k * 256 + tid;
    int c = idx & 63;
    outp[idx] = fmaf(h2[idx], sS2[c], sB2[c]);
  }
}

extern "C" void kernel_launch(void* const* d_in, const int* in_sizes, int n_in,
                              void* d_out, int out_size, void* d_ws, size_t ws_size,
                              hipStream_t stream) {
  const float* fea  = (const float*)d_in[0];
  const float* adj  = (const float*)d_in[1];
  const float* encW = (const float*)d_in[2];
  const float* encb = (const float*)d_in[3];
  const float* bondW= (const float*)d_in[4];
  const float* eps  = (const float*)d_in[5];
  const float* W1   = (const float*)d_in[6];
  const float* b1   = (const float*)d_in[7];
  const float* g1   = (const float*)d_in[8];
  const float* be1  = (const float*)d_in[9];
  const float* W2   = (const float*)d_in[10];
  const float* b2   = (const float*)d_in[11];
  const float* gbn  = (const float*)d_in[12];
  const float* bbn  = (const float*)d_in[13];
  float* out = (float*)d_out;
  float* ws  = (float*)d_ws;

  float* x   = ws;                 // 262144 floats (enc out / raw h2)
  float* h1  = ws + 262144;        // 524288 floats
  float* acc = ws + 786432;        // 3 layers x 512 slots x AST floats (padded)

  enc_kernel<<<1024, 256, 0, stream>>>(fea, encW, encb, x, acc);
  for (int l = 0; l < 3; ++l) {
    float* accl = acc + (size_t)l * 512 * AST;
    bc_kernel<<<GBC, 256, 0, stream>>>(
        adj, x, bondW + l * DD, eps + l, W1 + l * DD * D2, b1 + l * D2,
        l ? gbn + (l - 1) * DD : gbn, l ? bbn + (l - 1) * DD : bbn,
        l ? acc + (size_t)(l - 1) * 512 * AST + 256 * AST : acc, l > 0 ? 1 : 0,
        h1, accl);
    d_kernel<<<GBD, 256, 0, stream>>>(h1, W2 + l * D2 * DD, b2 + l * DD,
                                      g1 + l * D2, be1 + l * D2, x,
                                      accl, accl + 256 * AST);
  }
  fin_kernel<<<256, 256, 0, stream>>>(x, gbn + 2 * DD, bbn + 2 * DD,
                                      acc + (size_t)2 * 512 * AST + 256 * AST, out);
}